// Round 8
// baseline (142.159 us; speedup 1.0000x reference)
//
#include <hip/hip_runtime.h>

#define BATCH 8
#define NPTS 4096
#define KSEL 6          // K_NN + 1
#define ALPHA 1.05f

// --- bucketing (x-projection) ---
#define NBUCK 128
#define BUCK_L0 (-4.0f)
#define BUCK_W  (0.0625f)
#define BUCK_INVW 16.0f

static __device__ __forceinline__ unsigned umn(unsigned a, unsigned b) { return a < b ? a : b; }
static __device__ __forceinline__ unsigned umx(unsigned a, unsigned b) { return a > b ? a : b; }
#define FINF 0x7F800000u

static __device__ __forceinline__ int bucket_of(float x) {
  int bk = (int)((x - BUCK_L0) * BUCK_INVW);
  return bk < 0 ? 0 : (bk > NBUCK - 1 ? NBUCK - 1 : bk);
}

// insert one candidate into ascending sorted m[0..5] (branchless, exact)
static __device__ __forceinline__ void insert1(unsigned m[KSEL], unsigned t) {
#pragma unroll
  for (int q = 0; q < KSEL - 1; ++q) {
    const unsigned lo = umn(m[q], t);
    t = umx(m[q], t);
    m[q] = lo;
  }
  m[KSEL - 1] = umn(m[KSEL - 1], t);
}

// --- R5 fallback helpers (fused 2-candidate insert) ---
static __device__ __forceinline__ unsigned min3u(unsigned a, unsigned b, unsigned c) {
  unsigned d; asm("v_min3_u32 %0, %1, %2, %3" : "=v"(d) : "v"(a), "v"(b), "v"(c)); return d;
}
static __device__ __forceinline__ unsigned med3u(unsigned a, unsigned b, unsigned c) {
  unsigned d; asm("v_med3_u32 %0, %1, %2, %3" : "=v"(d) : "v"(a), "v"(b), "v"(c)); return d;
}
static __device__ __forceinline__ unsigned max3u(unsigned a, unsigned b, unsigned c) {
  unsigned d; asm("v_max3_u32 %0, %1, %2, %3" : "=v"(d) : "v"(a), "v"(b), "v"(c)); return d;
}
static __device__ __forceinline__ void insert2(unsigned m[KSEL], unsigned tA, unsigned tB) {
#pragma unroll
  for (int k = 0; k < KSEL - 1; ++k) {
    const unsigned mk = m[k];
    m[k] = min3u(mk, tA, tB);
    const unsigned nA = med3u(mk, tA, tB);
    const unsigned nB = max3u(mk, tA, tB);
    tA = nA; tB = nB;
  }
  m[KSEL - 1] = min3u(m[KSEL - 1], tA, tB);
}

// ---------------------------------------------------------------------------
// Kernel A: per-batch counting sort by x into NBUCK buckets (SoA output).
// grid = 8, block = 1024. Also zeroes out[0].
// ---------------------------------------------------------------------------
__global__ __launch_bounds__(1024) void bucket_kernel(const float* __restrict__ pc,
                                                      float* __restrict__ xs_g,
                                                      float* __restrict__ ys_g,
                                                      float* __restrict__ zs_g,
                                                      int* __restrict__ starts_g,
                                                      float* __restrict__ out) {
  __shared__ int hist[NBUCK];
  __shared__ int starts[NBUCK + 1];
  __shared__ int offs[NBUCK];
  const int b   = blockIdx.x;
  const int tid = threadIdx.x;
  if (b == 0 && tid == 0) out[0] = 0.0f;
  if (tid < NBUCK) hist[tid] = 0;
  __syncthreads();

  const float4* __restrict__ b4 = (const float4*)(pc + (size_t)b * (NPTS * 3));
  const float4 q0 = b4[tid * 3 + 0];   // x0 y0 z0 x1
  const float4 q1 = b4[tid * 3 + 1];   // y1 z1 x2 y2
  const float4 q2 = b4[tid * 3 + 2];   // z2 x3 y3 z3
  const float px[4] = {q0.x, q0.w, q1.z, q2.y};
  const float py[4] = {q0.y, q1.x, q1.w, q2.z};
  const float pz[4] = {q0.z, q1.y, q2.x, q2.w};
  int bk[4];
#pragma unroll
  for (int u = 0; u < 4; ++u) {
    bk[u] = bucket_of(px[u]);
    atomicAdd(&hist[bk[u]], 1);
  }
  __syncthreads();
  if (tid == 0) {
    int tot = 0;
    for (int i = 0; i < NBUCK; ++i) { starts[i] = tot; tot += hist[i]; }
    starts[NBUCK] = tot;   // == NPTS
  }
  __syncthreads();
  if (tid < NBUCK) offs[tid] = 0;
  if (tid <= NBUCK) starts_g[b * (NBUCK + 2) + tid] = starts[tid];
  __syncthreads();
#pragma unroll
  for (int u = 0; u < 4; ++u) {
    const int pos = starts[bk[u]] + atomicAdd(&offs[bk[u]], 1);
    xs_g[b * NPTS + pos] = px[u];
    ys_g[b * NPTS + pos] = py[u];
    zs_g[b * NPTS + pos] = pz[u];
  }
}

// ---------------------------------------------------------------------------
// Kernel B: pruned 5-NN scan. grid = 512 (b*64+tile), block = 512 (8 waves).
// Each wave owns 8 consecutive sorted points; 8 sub-lanes per point scan
// stride-8 interleaved candidates, expanding bucket rings around the home
// bucket. Direction terminates when (gap to bucket edge)^2 > shared 6th-best
// (shared = min over the 8 sub-lanes: valid upper bound on the point's true
// current 6th-best -> every skipped candidate has d > final 6th-best: EXACT).
// Epilogue: 3-level shfl_xor merge of the 8 partial top-6 lists.
// ---------------------------------------------------------------------------
__global__ __launch_bounds__(512, 4) void knn_scan_kernel(const float* __restrict__ xs_g,
                                                          const float* __restrict__ ys_g,
                                                          const float* __restrict__ zs_g,
                                                          const int* __restrict__ starts_g,
                                                          float* __restrict__ value) {
  __shared__ __align__(16) float xs[NPTS];
  __shared__ __align__(16) float ys[NPTS];
  __shared__ __align__(16) float zs[NPTS];
  __shared__ int st[NBUCK + 1];

  const int tid  = threadIdx.x;
  const int b    = blockIdx.x >> 6;
  const int tile = blockIdx.x & 63;

  {  // stage sorted SoA (L2-hot, coalesced float4)
    const float4* __restrict__ x4 = (const float4*)(xs_g + b * NPTS);
    const float4* __restrict__ y4 = (const float4*)(ys_g + b * NPTS);
    const float4* __restrict__ z4 = (const float4*)(zs_g + b * NPTS);
    ((float4*)xs)[tid] = x4[tid];  ((float4*)xs)[tid + 512] = x4[tid + 512];
    ((float4*)ys)[tid] = y4[tid];  ((float4*)ys)[tid + 512] = y4[tid + 512];
    ((float4*)zs)[tid] = z4[tid];  ((float4*)zs)[tid + 512] = z4[tid + 512];
  }
  if (tid <= NBUCK) st[tid] = starts_g[b * (NBUCK + 2) + tid];
  __syncthreads();

  const int lane = tid & 63;
  const int wave = tid >> 6;
  const int sub  = lane & 7;
  const int p    = tile * 64 + wave * 8 + (lane >> 3);   // sorted index

  const float xi = xs[p], yi = ys[p], zi = zs[p];
  const int hb = bucket_of(xi);

  unsigned m[KSEL];
#pragma unroll
  for (int k = 0; k < KSEL; ++k) m[k] = FINF;

  // home bucket (includes self: d == 0 exactly, dropped as the min later)
  {
    const int e = st[hb + 1];
    for (int j = st[hb] + sub; j < e; j += 8) {
      const float dx = xi - xs[j], dy = yi - ys[j], dz = zi - zs[j];
      const float d = fmaf(dz, dz, fmaf(dy, dy, dx * dx));
      insert1(m, __float_as_uint(d));
    }
  }

  bool ldone = false, rdone = false;
  for (int r = 1; r < NBUCK; ++r) {
    // share 6th-best across the point's 8 sub-lanes (uniform program point)
    unsigned m5s = m[KSEL - 1];
    m5s = umn(m5s, (unsigned)__shfl_xor((int)m5s, 1));
    m5s = umn(m5s, (unsigned)__shfl_xor((int)m5s, 2));
    m5s = umn(m5s, (unsigned)__shfl_xor((int)m5s, 4));
    const float bound = __uint_as_float(m5s);

    if (!ldone) {
      const int bk = hb - r;
      if (bk < 0) ldone = true;
      else {
        // remaining-left points have x <= right_edge(bk); gap >= 0
        const float gap = xi - (BUCK_L0 + (float)(bk + 1) * BUCK_W);
        if (gap * gap * 0.9999f > bound) ldone = true;
        else {
          const int e = st[bk + 1];
          for (int j = st[bk] + sub; j < e; j += 8) {
            const float dx = xi - xs[j], dy = yi - ys[j], dz = zi - zs[j];
            const float d = fmaf(dz, dz, fmaf(dy, dy, dx * dx));
            insert1(m, __float_as_uint(d));
          }
        }
      }
    }
    if (!rdone) {
      const int bk = hb + r;
      if (bk >= NBUCK) rdone = true;
      else {
        // remaining-right points have x >= left_edge(bk); gap >= 0
        const float gap = (BUCK_L0 + (float)bk * BUCK_W) - xi;
        if (gap * gap * 0.9999f > bound) rdone = true;
        else {
          const int e = st[bk + 1];
          for (int j = st[bk] + sub; j < e; j += 8) {
            const float dx = xi - xs[j], dy = yi - ys[j], dz = zi - zs[j];
            const float d = fmaf(dz, dz, fmaf(dy, dy, dx * dx));
            insert1(m, __float_as_uint(d));
          }
        }
      }
    }
    if (__all(ldone && rdone)) break;
  }

  // merge the 8 sub-lane lists (in-register, XOR tree)
#pragma unroll
  for (int lvl = 1; lvl <= 4; lvl <<= 1) {
    unsigned bb[KSEL];
#pragma unroll
    for (int k = 0; k < KSEL; ++k) bb[k] = (unsigned)__shfl_xor((int)m[k], lvl);
#pragma unroll
    for (int k = 0; k < KSEL; ++k) insert1(m, bb[k]);
  }

  if (sub == 0) {
    float s5 = 0.f;
#pragma unroll
    for (int k = 1; k < KSEL; ++k) s5 += __uint_as_float(m[k]);
    value[b * NPTS + p] = s5 * 0.2f;   // sorted order; stats is order-agnostic
  }
}

// ---------------------------------------------------------------------------
// Fallback: R5 brute-force kernel (proven 51 µs) if ws_size is too small.
// grid = 512, block = 1024 (16 waves), LDS SoA + segmented scan + tree merge.
// ---------------------------------------------------------------------------
#define NSEG 16
#define SEGLEN (NPTS / NSEG)
__global__ __launch_bounds__(1024) void knn_brute_kernel(const float* __restrict__ pc,
                                                         float* __restrict__ value,
                                                         float* __restrict__ out) {
  __shared__ union __align__(16) {
    struct { float xs[NPTS]; float ys[NPTS]; float zs[NPTS]; } s;
    unsigned cand[NSEG][64][KSEL];
  } sh;

  const int tid = threadIdx.x;
  const int pt  = tid & 63;
  const int seg = __builtin_amdgcn_readfirstlane(tid >> 6);
  const int b    = blockIdx.x >> 6;
  const int tile = blockIdx.x & 63;
  const int i    = tile * 64 + pt;

  if (blockIdx.x == 0 && tid == 0) out[0] = 0.0f;

  const float* __restrict__ base = pc + (size_t)b * (NPTS * 3);
  {
    const float4* __restrict__ b4 = (const float4*)base;
    const float4 q0 = b4[tid * 3 + 0];
    const float4 q1 = b4[tid * 3 + 1];
    const float4 q2 = b4[tid * 3 + 2];
    const int p0 = tid * 4;
    sh.s.xs[p0 + 0] = q0.x; sh.s.ys[p0 + 0] = q0.y; sh.s.zs[p0 + 0] = q0.z;
    sh.s.xs[p0 + 1] = q0.w; sh.s.ys[p0 + 1] = q1.x; sh.s.zs[p0 + 1] = q1.y;
    sh.s.xs[p0 + 2] = q1.z; sh.s.ys[p0 + 2] = q1.w; sh.s.zs[p0 + 2] = q2.x;
    sh.s.xs[p0 + 3] = q2.y; sh.s.ys[p0 + 3] = q2.z; sh.s.zs[p0 + 3] = q2.w;
  }
  __syncthreads();

  const float xi = sh.s.xs[i], yi = sh.s.ys[i], zi = sh.s.zs[i];
  unsigned m[KSEL];
#pragma unroll
  for (int k = 0; k < KSEL; ++k) m[k] = FINF;

  const int j0 = seg * SEGLEN;
#pragma unroll 4
  for (int jj = 0; jj < SEGLEN; jj += 4) {
    const float4 cx = *(const float4*)&sh.s.xs[j0 + jj];
    const float4 cy = *(const float4*)&sh.s.ys[j0 + jj];
    const float4 cz = *(const float4*)&sh.s.zs[j0 + jj];
    const float dxA = xi - cx.x, dyA = yi - cy.x, dzA = zi - cz.x;
    const float dxB = xi - cx.y, dyB = yi - cy.y, dzB = zi - cz.y;
    const float dxC = xi - cx.z, dyC = yi - cy.z, dzC = zi - cz.z;
    const float dxD = xi - cx.w, dyD = yi - cy.w, dzD = zi - cz.w;
    float dA = dxA * dxA, dB = dxB * dxB, dC = dxC * dxC, dD = dxD * dxD;
    dA = fmaf(dyA, dyA, dA); dB = fmaf(dyB, dyB, dB);
    dC = fmaf(dyC, dyC, dC); dD = fmaf(dyD, dyD, dD);
    dA = fmaf(dzA, dzA, dA); dB = fmaf(dzB, dzB, dB);
    dC = fmaf(dzC, dzC, dC); dD = fmaf(dzD, dzD, dD);
    insert2(m, __float_as_uint(dA), __float_as_uint(dB));
    insert2(m, __float_as_uint(dC), __float_as_uint(dD));
  }
  __syncthreads();
#pragma unroll
  for (int k = 0; k < KSEL; ++k) sh.cand[seg][pt][k] = m[k];
  __syncthreads();

  for (int stg = 1; stg < NSEG; stg <<= 1) {
    const int pairs = NSEG / (2 * stg);
    if (tid < pairs * 64) {
      const int q = tid >> 6;
      const int pp = tid & 63;
      unsigned* A = &sh.cand[2 * stg * q][pp][0];
      const unsigned* B = &sh.cand[2 * stg * q + stg][pp][0];
      unsigned mm[KSEL];
#pragma unroll
      for (int k = 0; k < KSEL; ++k) mm[k] = A[k];
#pragma unroll
      for (int k = 0; k < KSEL; ++k) {
        unsigned t = B[k];
#pragma unroll
        for (int u = 0; u < KSEL - 1; ++u) {
          const unsigned lo = umn(mm[u], t);
          t = umx(mm[u], t);
          mm[u] = lo;
        }
        mm[KSEL - 1] = umn(mm[KSEL - 1], t);
      }
#pragma unroll
      for (int k = 0; k < KSEL; ++k) A[k] = mm[k];
    }
    __syncthreads();
  }
  if (tid < 64) {
    float s5 = 0.f;
#pragma unroll
    for (int k = 1; k < KSEL; ++k) s5 += __uint_as_float(sh.cand[0][tid][k]);
    value[b * NPTS + tile * 64 + tid] = s5 * 0.2f;
  }
}

// ---------------------------------------------------------------------------
// Kernel C: per-batch mean / unbiased std / threshold / masked mean * weight,
// atomicAdd of loss/BATCH into out (zeroed upstream).
// ---------------------------------------------------------------------------
__global__ __launch_bounds__(256) void stats_kernel(const float* __restrict__ value,
                                                    const float* __restrict__ weights,
                                                    float* __restrict__ out) {
  __shared__ float red[256];
  const int b   = blockIdx.x;
  const int tid = threadIdx.x;
  const float* __restrict__ v = value + b * NPTS;

  float s = 0.f;
  for (int j = tid; j < NPTS; j += 256) s += v[j];
  red[tid] = s;
  __syncthreads();
  for (int off = 128; off > 0; off >>= 1) {
    if (tid < off) red[tid] += red[tid + off];
    __syncthreads();
  }
  const float mean = red[0] * (1.0f / NPTS);
  __syncthreads();

  float s2 = 0.f;
  for (int j = tid; j < NPTS; j += 256) {
    const float d = v[j] - mean;
    s2 += d * d;
  }
  red[tid] = s2;
  __syncthreads();
  for (int off = 128; off > 0; off >>= 1) {
    if (tid < off) red[tid] += red[tid + off];
    __syncthreads();
  }
  const float thr = mean + ALPHA * sqrtf(red[0] * (1.0f / (NPTS - 1)));
  __syncthreads();

  float s3 = 0.f;
  for (int j = tid; j < NPTS; j += 256) {
    const float vv = v[j];
    if (vv > thr) s3 += vv;
  }
  red[tid] = s3;
  __syncthreads();
  for (int off = 128; off > 0; off >>= 1) {
    if (tid < off) red[tid] += red[tid + off];
    __syncthreads();
  }
  if (tid == 0) {
    atomicAdd(out, red[0] * (1.0f / NPTS) * weights[b] * (1.0f / BATCH));
  }
}

extern "C" void kernel_launch(void* const* d_in, const int* in_sizes, int n_in,
                              void* d_out, int out_size, void* d_ws, size_t ws_size,
                              hipStream_t stream) {
  const float* pc      = (const float*)d_in[0];   // [8,4096,3] f32
  const float* weights = (const float*)d_in[1];   // [8] f32
  float* out   = (float*)d_out;                   // scalar f32
  float* value = (float*)d_ws;                    // [8*4096]

  const size_t need = (size_t)(32768 * 4) * sizeof(float) + (size_t)BATCH * (NBUCK + 2) * sizeof(int);
  if (ws_size >= need + 1024) {
    float* xs_g = value + 32768;
    float* ys_g = xs_g + 32768;
    float* zs_g = ys_g + 32768;
    int* starts_g = (int*)(zs_g + 32768);
    bucket_kernel<<<dim3(BATCH), dim3(1024), 0, stream>>>(pc, xs_g, ys_g, zs_g, starts_g, out);
    knn_scan_kernel<<<dim3(BATCH * 64), dim3(512), 0, stream>>>(xs_g, ys_g, zs_g, starts_g, value);
  } else {
    knn_brute_kernel<<<dim3(BATCH * 64), dim3(1024), 0, stream>>>(pc, value, out);
  }
  stats_kernel<<<dim3(BATCH), dim3(256), 0, stream>>>(value, weights, out);
}

// Round 9
// 119.871 us; speedup vs baseline: 1.1859x; 1.1859x over previous
//
#include <hip/hip_runtime.h>

#define BATCH 8
#define NPTS 4096
#define KSEL 6          // K_NN + 1
#define ALPHA 1.05f
#define NSEG 16         // window split across 16 waves
#define WPAD 192        // stage-A fixed half-window (in sorted-index space)

// --- bucketing (x-projection) ---
#define NBUCK 128
#define BUCK_L0 (-4.0f)
#define BUCK_W  (0.0625f)
#define BUCK_INVW 16.0f

static __device__ __forceinline__ unsigned umn(unsigned a, unsigned b) { return a < b ? a : b; }
static __device__ __forceinline__ unsigned umx(unsigned a, unsigned b) { return a > b ? a : b; }
#define FINF 0x7F800000u

static __device__ __forceinline__ int bucket_of(float x) {
  int bk = (int)((x - BUCK_L0) * BUCK_INVW);
  return bk < 0 ? 0 : (bk > NBUCK - 1 ? NBUCK - 1 : bk);
}

static __device__ __forceinline__ unsigned min3u(unsigned a, unsigned b, unsigned c) {
  unsigned d; asm("v_min3_u32 %0, %1, %2, %3" : "=v"(d) : "v"(a), "v"(b), "v"(c)); return d;
}
static __device__ __forceinline__ unsigned med3u(unsigned a, unsigned b, unsigned c) {
  unsigned d; asm("v_med3_u32 %0, %1, %2, %3" : "=v"(d) : "v"(a), "v"(b), "v"(c)); return d;
}
static __device__ __forceinline__ unsigned max3u(unsigned a, unsigned b, unsigned c) {
  unsigned d; asm("v_max3_u32 %0, %1, %2, %3" : "=v"(d) : "v"(a), "v"(b), "v"(c)); return d;
}

// fused branchless insert of 2 candidates (bit-identical to sequential; R2-R7)
static __device__ __forceinline__ void insert2(unsigned m[KSEL], unsigned tA, unsigned tB) {
#pragma unroll
  for (int k = 0; k < KSEL - 1; ++k) {
    const unsigned mk = m[k];
    m[k] = min3u(mk, tA, tB);
    const unsigned nA = med3u(mk, tA, tB);
    const unsigned nB = max3u(mk, tA, tB);
    tA = nA; tB = nB;
  }
  m[KSEL - 1] = min3u(m[KSEL - 1], tA, tB);
}
// single-candidate insert (guarded tails only)
static __device__ __forceinline__ void insert1(unsigned m[KSEL], unsigned t) {
#pragma unroll
  for (int q = 0; q < KSEL - 1; ++q) {
    const unsigned lo = umn(m[q], t);
    t = umx(m[q], t);
    m[q] = lo;
  }
  m[KSEL - 1] = umn(m[KSEL - 1], t);
}

// ---------------------------------------------------------------------------
// Kernel A: per-batch counting sort by x into NBUCK buckets (SoA output).
// grid = 8, block = 1024. Also zeroes out[0]. (Proven R8.)
// ---------------------------------------------------------------------------
__global__ __launch_bounds__(1024) void bucket_kernel(const float* __restrict__ pc,
                                                      float* __restrict__ xs_g,
                                                      float* __restrict__ ys_g,
                                                      float* __restrict__ zs_g,
                                                      int* __restrict__ starts_g,
                                                      float* __restrict__ out) {
  __shared__ int hist[NBUCK];
  __shared__ int starts[NBUCK + 1];
  __shared__ int offs[NBUCK];
  const int b   = blockIdx.x;
  const int tid = threadIdx.x;
  if (b == 0 && tid == 0) out[0] = 0.0f;
  if (tid < NBUCK) hist[tid] = 0;
  __syncthreads();

  const float4* __restrict__ b4 = (const float4*)(pc + (size_t)b * (NPTS * 3));
  const float4 q0 = b4[tid * 3 + 0];
  const float4 q1 = b4[tid * 3 + 1];
  const float4 q2 = b4[tid * 3 + 2];
  const float px[4] = {q0.x, q0.w, q1.z, q2.y};
  const float py[4] = {q0.y, q1.x, q1.w, q2.z};
  const float pz[4] = {q0.z, q1.y, q2.x, q2.w};
  int bk[4];
#pragma unroll
  for (int u = 0; u < 4; ++u) {
    bk[u] = bucket_of(px[u]);
    atomicAdd(&hist[bk[u]], 1);
  }
  __syncthreads();
  if (tid == 0) {
    int tot = 0;
    for (int i = 0; i < NBUCK; ++i) { starts[i] = tot; tot += hist[i]; }
    starts[NBUCK] = tot;
  }
  __syncthreads();
  if (tid < NBUCK) offs[tid] = 0;
  if (tid <= NBUCK) starts_g[b * (NBUCK + 2) + tid] = starts[tid];
  __syncthreads();
#pragma unroll
  for (int u = 0; u < 4; ++u) {
    const int pos = starts[bk[u]] + atomicAdd(&offs[bk[u]], 1);
    xs_g[b * NPTS + pos] = px[u];
    ys_g[b * NPTS + pos] = py[u];
    zs_g[b * NPTS + pos] = pz[u];
  }
}

// ---------------------------------------------------------------------------
// Kernel B: windowed 5-NN. R5 engine (1024 thr, 16 waves, lane=point,
// broadcast chunks + insert2) but scanning only an x-window.
//  Stage A: fixed window [g0-WPAD, g1+WPAD) -> per-lane seed top-6.
//  Bound:   block-max of 6th-best -> r -> exact bucket window [jlo,jhi).
//  Stage B: remainder [jlo,wlo) U [whi,jhi).  Exact: excluded j have
//           dx^2 > r^2 >= m5_seed >= m5_final (strict).
// grid = 512 (b*64+tile), LDS 73 KB -> 2 blocks/CU, 32 waves/CU.
// ---------------------------------------------------------------------------
__global__ __launch_bounds__(1024) void knn_window_kernel(const float* __restrict__ xs_g,
                                                          const float* __restrict__ ys_g,
                                                          const float* __restrict__ zs_g,
                                                          const int* __restrict__ starts_g,
                                                          float* __restrict__ value) {
  __shared__ __align__(16) float xs[NPTS];
  __shared__ __align__(16) float ys[NPTS];
  __shared__ __align__(16) float zs[NPTS];
  __shared__ unsigned cand[NSEG][64][KSEL];
  __shared__ int st[NBUCK + 1];
  __shared__ unsigned wred[NSEG];

  const int tid  = threadIdx.x;
  const int b    = blockIdx.x >> 6;
  const int tile = blockIdx.x & 63;
  const int g0   = tile * 64;

  {  // stage sorted SoA: 1024 float4 loads per array
    const float4* __restrict__ x4 = (const float4*)(xs_g + b * NPTS);
    const float4* __restrict__ y4 = (const float4*)(ys_g + b * NPTS);
    const float4* __restrict__ z4 = (const float4*)(zs_g + b * NPTS);
    ((float4*)xs)[tid] = x4[tid];
    ((float4*)ys)[tid] = y4[tid];
    ((float4*)zs)[tid] = z4[tid];
  }
  if (tid <= NBUCK) st[tid] = starts_g[b * (NBUCK + 2) + tid];
  __syncthreads();

  const int lane = tid & 63;
  const int wv   = tid >> 6;
  const int i    = g0 + lane;
  const float xi = xs[i], yi = ys[i], zi = zs[i];

  unsigned m[KSEL];
#pragma unroll
  for (int k = 0; k < KSEL; ++k) m[k] = FINF;

  // packed chunk scan (4 candidates, broadcast)
  auto do_chunk = [&](int j) {
    const float4 cx = *(const float4*)&xs[j];
    const float4 cy = *(const float4*)&ys[j];
    const float4 cz = *(const float4*)&zs[j];
    const float dxA = xi - cx.x, dyA = yi - cy.x, dzA = zi - cz.x;
    const float dxB = xi - cx.y, dyB = yi - cy.y, dzB = zi - cz.y;
    const float dxC = xi - cx.z, dyC = yi - cy.z, dzC = zi - cz.z;
    const float dxD = xi - cx.w, dyD = yi - cy.w, dzD = zi - cz.w;
    float dA = dxA * dxA, dB = dxB * dxB, dC = dxC * dxC, dD = dxD * dxD;
    dA = fmaf(dyA, dyA, dA); dB = fmaf(dyB, dyB, dB);
    dC = fmaf(dyC, dyC, dC); dD = fmaf(dyD, dyD, dD);
    dA = fmaf(dzA, dzA, dA); dB = fmaf(dzB, dzB, dB);
    dC = fmaf(dzC, dzC, dC); dD = fmaf(dzD, dzD, dD);
    insert2(m, __float_as_uint(dA), __float_as_uint(dB));
    insert2(m, __float_as_uint(dC), __float_as_uint(dD));
  };

  // ---- stage A: fixed window (all bounds multiples of 4)
  const int wlo = (g0 - WPAD) > 0 ? (g0 - WPAD) : 0;
  const int whi = (g0 + 64 + WPAD) < NPTS ? (g0 + 64 + WPAD) : NPTS;
  const int ncA = (whi - wlo) >> 2;
  for (int c = wv; c < ncA; c += NSEG) do_chunk(wlo + (c << 2));

  // ---- block-level bound: max over all lanes/waves of 6th-best
  {
    unsigned v = m[KSEL - 1];
#pragma unroll
    for (int s = 1; s < 64; s <<= 1) v = umx(v, (unsigned)__shfl_xor((int)v, s));
    if (lane == 0) wred[wv] = v;
  }
  __syncthreads();
  unsigned bm = wred[0];
#pragma unroll
  for (int k = 1; k < NSEG; ++k) bm = umx(bm, wred[k]);

  // group x-extent (every wave holds the same 64 points)
  float gxmin = xi, gxmax = xi;
#pragma unroll
  for (int s = 1; s < 64; s <<= 1) {
    gxmin = fminf(gxmin, __shfl_xor(gxmin, s));
    gxmax = fmaxf(gxmax, __shfl_xor(gxmax, s));
  }

  const float r   = sqrtf(__uint_as_float(bm)) * 1.0001f;
  const int   blo = bucket_of(gxmin - r);
  const int   bhi = bucket_of(gxmax + r);
  const int   jlo = st[blo];
  const int   jhi = st[bhi + 1];

  // ---- stage B: remainder, wave-uniform chunk stride, guarded tails
  auto scan_side = [&](int base, int len) {
    if (len <= 0) return;
    const int nc = (len + 3) >> 2;
    for (int c = wv; c < nc; c += NSEG) {
      const int j = base + (c << 2);
      if (j + 4 <= base + len) {
        do_chunk(j);
      } else {
        for (int jj = j; jj < base + len; ++jj) {
          const float dx = xi - xs[jj], dy = yi - ys[jj], dz = zi - zs[jj];
          insert1(m, __float_as_uint(fmaf(dz, dz, fmaf(dy, dy, dx * dx))));
        }
      }
    }
  };
  scan_side(jlo, wlo - jlo);    // left of stage-A window
  scan_side(whi, jhi - whi);    // right of stage-A window
  __syncthreads();              // xs/ys/zs reads done (cand is separate)

#pragma unroll
  for (int k = 0; k < KSEL; ++k) cand[wv][lane][k] = m[k];
  __syncthreads();

  // tree-merge the 16 sorted lists per point (proven R5)
  for (int stg = 1; stg < NSEG; stg <<= 1) {
    const int pairs = NSEG / (2 * stg);
    if (tid < pairs * 64) {
      const int q = tid >> 6;
      const int pp = tid & 63;
      unsigned* A = &cand[2 * stg * q][pp][0];
      const unsigned* B = &cand[2 * stg * q + stg][pp][0];
      unsigned mm[KSEL];
#pragma unroll
      for (int k = 0; k < KSEL; ++k) mm[k] = A[k];
#pragma unroll
      for (int k = 0; k < KSEL; ++k) {
        unsigned t = B[k];
#pragma unroll
        for (int u = 0; u < KSEL - 1; ++u) {
          const unsigned lo = umn(mm[u], t);
          t = umx(mm[u], t);
          mm[u] = lo;
        }
        mm[KSEL - 1] = umn(mm[KSEL - 1], t);
      }
#pragma unroll
      for (int k = 0; k < KSEL; ++k) A[k] = mm[k];
    }
    __syncthreads();
  }

  // drop self (exact 0 = min), mean of remaining 5; sorted order is fine
  if (tid < 64) {
    float s5 = 0.f;
#pragma unroll
    for (int k = 1; k < KSEL; ++k) s5 += __uint_as_float(cand[0][tid][k]);
    value[b * NPTS + g0 + tid] = s5 * 0.2f;
  }
}

// ---------------------------------------------------------------------------
// Kernel C: per-batch stats + masked mean * weight -> atomicAdd into out.
// ---------------------------------------------------------------------------
__global__ __launch_bounds__(256) void stats_kernel(const float* __restrict__ value,
                                                    const float* __restrict__ weights,
                                                    float* __restrict__ out) {
  __shared__ float red[256];
  const int b   = blockIdx.x;
  const int tid = threadIdx.x;
  const float* __restrict__ v = value + b * NPTS;

  float s = 0.f;
  for (int j = tid; j < NPTS; j += 256) s += v[j];
  red[tid] = s;
  __syncthreads();
  for (int off = 128; off > 0; off >>= 1) {
    if (tid < off) red[tid] += red[tid + off];
    __syncthreads();
  }
  const float mean = red[0] * (1.0f / NPTS);
  __syncthreads();

  float s2 = 0.f;
  for (int j = tid; j < NPTS; j += 256) {
    const float d = v[j] - mean;
    s2 += d * d;
  }
  red[tid] = s2;
  __syncthreads();
  for (int off = 128; off > 0; off >>= 1) {
    if (tid < off) red[tid] += red[tid + off];
    __syncthreads();
  }
  const float thr = mean + ALPHA * sqrtf(red[0] * (1.0f / (NPTS - 1)));
  __syncthreads();

  float s3 = 0.f;
  for (int j = tid; j < NPTS; j += 256) {
    const float vv = v[j];
    if (vv > thr) s3 += vv;
  }
  red[tid] = s3;
  __syncthreads();
  for (int off = 128; off > 0; off >>= 1) {
    if (tid < off) red[tid] += red[tid + off];
    __syncthreads();
  }
  if (tid == 0) {
    atomicAdd(out, red[0] * (1.0f / NPTS) * weights[b] * (1.0f / BATCH));
  }
}

extern "C" void kernel_launch(void* const* d_in, const int* in_sizes, int n_in,
                              void* d_out, int out_size, void* d_ws, size_t ws_size,
                              hipStream_t stream) {
  const float* pc      = (const float*)d_in[0];   // [8,4096,3] f32
  const float* weights = (const float*)d_in[1];   // [8] f32
  float* out   = (float*)d_out;                   // scalar f32
  float* value = (float*)d_ws;                    // [8*4096]

  float* xs_g = value + 32768;
  float* ys_g = xs_g + 32768;
  float* zs_g = ys_g + 32768;
  int* starts_g = (int*)(zs_g + 32768);

  bucket_kernel<<<dim3(BATCH), dim3(1024), 0, stream>>>(pc, xs_g, ys_g, zs_g, starts_g, out);
  knn_window_kernel<<<dim3(BATCH * 64), dim3(1024), 0, stream>>>(xs_g, ys_g, zs_g, starts_g, value);
  stats_kernel<<<dim3(BATCH), dim3(256), 0, stream>>>(value, weights, out);
}

// Round 10
// 117.740 us; speedup vs baseline: 1.2074x; 1.0181x over previous
//
#include <hip/hip_runtime.h>

#define BATCH 8
#define NPTS 4096
#define KSEL 6          // K_NN + 1
#define ALPHA 1.05f
#define NSEG 16         // window split across 16 waves
#define WPAD 192        // stage-A fixed half-window (sorted-index space)

// --- bucketing (x-projection) ---
#define NBUCK 128
#define BUCK_L0 (-4.0f)
#define BUCK_W  (0.0625f)
#define BUCK_INVW 16.0f

static __device__ __forceinline__ unsigned umn(unsigned a, unsigned b) { return a < b ? a : b; }
static __device__ __forceinline__ unsigned umx(unsigned a, unsigned b) { return a > b ? a : b; }
#define FINF 0x7F800000u

static __device__ __forceinline__ int bucket_of(float x) {
  int bk = (int)((x - BUCK_L0) * BUCK_INVW);
  return bk < 0 ? 0 : (bk > NBUCK - 1 ? NBUCK - 1 : bk);
}

static __device__ __forceinline__ unsigned min3u(unsigned a, unsigned b, unsigned c) {
  unsigned d; asm("v_min3_u32 %0, %1, %2, %3" : "=v"(d) : "v"(a), "v"(b), "v"(c)); return d;
}
static __device__ __forceinline__ unsigned med3u(unsigned a, unsigned b, unsigned c) {
  unsigned d; asm("v_med3_u32 %0, %1, %2, %3" : "=v"(d) : "v"(a), "v"(b), "v"(c)); return d;
}
static __device__ __forceinline__ unsigned max3u(unsigned a, unsigned b, unsigned c) {
  unsigned d; asm("v_max3_u32 %0, %1, %2, %3" : "=v"(d) : "v"(a), "v"(b), "v"(c)); return d;
}

// fused branchless insert of 2 candidates (bit-identical to sequential; R2-R9)
static __device__ __forceinline__ void insert2(unsigned m[KSEL], unsigned tA, unsigned tB) {
#pragma unroll
  for (int k = 0; k < KSEL - 1; ++k) {
    const unsigned mk = m[k];
    m[k] = min3u(mk, tA, tB);
    const unsigned nA = med3u(mk, tA, tB);
    const unsigned nB = max3u(mk, tA, tB);
    tA = nA; tB = nB;
  }
  m[KSEL - 1] = min3u(m[KSEL - 1], tA, tB);
}
static __device__ __forceinline__ void insert1(unsigned m[KSEL], unsigned t) {
#pragma unroll
  for (int q = 0; q < KSEL - 1; ++q) {
    const unsigned lo = umn(m[q], t);
    t = umx(m[q], t);
    m[q] = lo;
  }
  m[KSEL - 1] = umn(m[KSEL - 1], t);
}

// ---------------------------------------------------------------------------
// Kernel A: per-batch counting sort by x into NBUCK buckets (SoA output).
// grid = 8, block = 1024. Also zeroes out[0]. (Proven R8/R9.)
// ---------------------------------------------------------------------------
__global__ __launch_bounds__(1024) void bucket_kernel(const float* __restrict__ pc,
                                                      float* __restrict__ xs_g,
                                                      float* __restrict__ ys_g,
                                                      float* __restrict__ zs_g,
                                                      int* __restrict__ starts_g,
                                                      float* __restrict__ out) {
  __shared__ int hist[NBUCK];
  __shared__ int starts[NBUCK + 1];
  __shared__ int offs[NBUCK];
  const int b   = blockIdx.x;
  const int tid = threadIdx.x;
  if (b == 0 && tid == 0) out[0] = 0.0f;
  if (tid < NBUCK) hist[tid] = 0;
  __syncthreads();

  const float4* __restrict__ b4 = (const float4*)(pc + (size_t)b * (NPTS * 3));
  const float4 q0 = b4[tid * 3 + 0];
  const float4 q1 = b4[tid * 3 + 1];
  const float4 q2 = b4[tid * 3 + 2];
  const float px[4] = {q0.x, q0.w, q1.z, q2.y};
  const float py[4] = {q0.y, q1.x, q1.w, q2.z};
  const float pz[4] = {q0.z, q1.y, q2.x, q2.w};
  int bk[4];
#pragma unroll
  for (int u = 0; u < 4; ++u) {
    bk[u] = bucket_of(px[u]);
    atomicAdd(&hist[bk[u]], 1);
  }
  __syncthreads();
  if (tid == 0) {
    int tot = 0;
    for (int i = 0; i < NBUCK; ++i) { starts[i] = tot; tot += hist[i]; }
    starts[NBUCK] = tot;
  }
  __syncthreads();
  if (tid < NBUCK) offs[tid] = 0;
  if (tid <= NBUCK) starts_g[b * (NBUCK + 2) + tid] = starts[tid];
  __syncthreads();
#pragma unroll
  for (int u = 0; u < 4; ++u) {
    const int pos = starts[bk[u]] + atomicAdd(&offs[bk[u]], 1);
    xs_g[b * NPTS + pos] = px[u];
    ys_g[b * NPTS + pos] = py[u];
    zs_g[b * NPTS + pos] = pz[u];
  }
}

// ---------------------------------------------------------------------------
// Kernel B: windowed 5-NN, R5 engine + CORRECTED bound (R9 post-mortem:
// old bound took MAX of unmerged per-wave 6th-bests -> no pruning).
// New: bound_p = MIN over waves of partial m[5]  (6th-smallest of any >=6
// subset upper-bounds the union's 6th-smallest), bm = max over points.
// ---------------------------------------------------------------------------
__global__ __launch_bounds__(1024) void knn_window_kernel(const float* __restrict__ xs_g,
                                                          const float* __restrict__ ys_g,
                                                          const float* __restrict__ zs_g,
                                                          const int* __restrict__ starts_g,
                                                          float* __restrict__ value) {
  __shared__ __align__(16) float xs[NPTS];
  __shared__ __align__(16) float ys[NPTS];
  __shared__ __align__(16) float zs[NPTS];
  __shared__ unsigned cand[NSEG][64][KSEL];
  __shared__ unsigned bnd[NSEG][64];
  __shared__ int st[NBUCK + 1];

  const int tid  = threadIdx.x;
  const int b    = blockIdx.x >> 6;
  const int tile = blockIdx.x & 63;
  const int g0   = tile * 64;

  {  // stage sorted SoA
    const float4* __restrict__ x4 = (const float4*)(xs_g + b * NPTS);
    const float4* __restrict__ y4 = (const float4*)(ys_g + b * NPTS);
    const float4* __restrict__ z4 = (const float4*)(zs_g + b * NPTS);
    ((float4*)xs)[tid] = x4[tid];
    ((float4*)ys)[tid] = y4[tid];
    ((float4*)zs)[tid] = z4[tid];
  }
  if (tid <= NBUCK) st[tid] = starts_g[b * (NBUCK + 2) + tid];
  __syncthreads();

  const int lane = tid & 63;
  const int wv   = tid >> 6;
  const int i    = g0 + lane;
  const float xi = xs[i], yi = ys[i], zi = zs[i];

  unsigned m[KSEL];
#pragma unroll
  for (int k = 0; k < KSEL; ++k) m[k] = FINF;

  auto do_chunk = [&](int j) {
    const float4 cx = *(const float4*)&xs[j];
    const float4 cy = *(const float4*)&ys[j];
    const float4 cz = *(const float4*)&zs[j];
    const float dxA = xi - cx.x, dyA = yi - cy.x, dzA = zi - cz.x;
    const float dxB = xi - cx.y, dyB = yi - cy.y, dzB = zi - cz.y;
    const float dxC = xi - cx.z, dyC = yi - cy.z, dzC = zi - cz.z;
    const float dxD = xi - cx.w, dyD = yi - cy.w, dzD = zi - cz.w;
    float dA = dxA * dxA, dB = dxB * dxB, dC = dxC * dxC, dD = dxD * dxD;
    dA = fmaf(dyA, dyA, dA); dB = fmaf(dyB, dyB, dB);
    dC = fmaf(dyC, dyC, dC); dD = fmaf(dyD, dyD, dD);
    dA = fmaf(dzA, dzA, dA); dB = fmaf(dzB, dzB, dB);
    dC = fmaf(dzC, dzC, dC); dD = fmaf(dzD, dzD, dD);
    insert2(m, __float_as_uint(dA), __float_as_uint(dB));
    insert2(m, __float_as_uint(dC), __float_as_uint(dD));
  };

  // ---- stage A: fixed window (bounds multiples of 4); >=16 cands per wave
  const int wlo = (g0 - WPAD) > 0 ? (g0 - WPAD) : 0;
  const int whi = (g0 + 64 + WPAD) < NPTS ? (g0 + 64 + WPAD) : NPTS;
  const int ncA = (whi - wlo) >> 2;
  for (int c = wv; c < ncA; c += NSEG) do_chunk(wlo + (c << 2));

  // ---- corrected bound
  bnd[wv][lane] = m[KSEL - 1];
  __syncthreads();
  unsigned bp = bnd[0][lane];
#pragma unroll
  for (int k = 1; k < NSEG; ++k) bp = umn(bp, bnd[k][lane]);  // per-point UB
  unsigned bm = bp;
#pragma unroll
  for (int s = 1; s < 64; s <<= 1) bm = umx(bm, (unsigned)__shfl_xor((int)bm, s));

  // group x-extent (every wave holds the same 64 points)
  float gxmin = xi, gxmax = xi;
#pragma unroll
  for (int s = 1; s < 64; s <<= 1) {
    gxmin = fminf(gxmin, __shfl_xor(gxmin, s));
    gxmax = fmaxf(gxmax, __shfl_xor(gxmax, s));
  }

  const float r   = sqrtf(__uint_as_float(bm)) * 1.0001f;
  const int   blo = bucket_of(gxmin - r);
  const int   bhi = bucket_of(gxmax + r);
  const int   jlo = st[blo];
  const int   jhi = st[bhi + 1];

  // ---- stage B: remainder, wave-uniform chunk stride, guarded tails
  auto scan_side = [&](int base, int len) {
    if (len <= 0) return;
    const int nc = (len + 3) >> 2;
    for (int c = wv; c < nc; c += NSEG) {
      const int j = base + (c << 2);
      if (j + 4 <= base + len) {
        do_chunk(j);
      } else {
        for (int jj = j; jj < base + len; ++jj) {
          const float dx = xi - xs[jj], dy = yi - ys[jj], dz = zi - zs[jj];
          insert1(m, __float_as_uint(fmaf(dz, dz, fmaf(dy, dy, dx * dx))));
        }
      }
    }
  };
  scan_side(jlo, wlo - jlo);
  scan_side(whi, jhi - whi);
  __syncthreads();

#pragma unroll
  for (int k = 0; k < KSEL; ++k) cand[wv][lane][k] = m[k];
  __syncthreads();

  // tree-merge the 16 sorted lists per point (proven R5)
  for (int stg = 1; stg < NSEG; stg <<= 1) {
    const int pairs = NSEG / (2 * stg);
    if (tid < pairs * 64) {
      const int q = tid >> 6;
      const int pp = tid & 63;
      unsigned* A = &cand[2 * stg * q][pp][0];
      const unsigned* B = &cand[2 * stg * q + stg][pp][0];
      unsigned mm[KSEL];
#pragma unroll
      for (int k = 0; k < KSEL; ++k) mm[k] = A[k];
#pragma unroll
      for (int k = 0; k < KSEL; ++k) {
        unsigned t = B[k];
#pragma unroll
        for (int u = 0; u < KSEL - 1; ++u) {
          const unsigned lo = umn(mm[u], t);
          t = umx(mm[u], t);
          mm[u] = lo;
        }
        mm[KSEL - 1] = umn(mm[KSEL - 1], t);
      }
#pragma unroll
      for (int k = 0; k < KSEL; ++k) A[k] = mm[k];
    }
    __syncthreads();
  }

  // drop self (exact 0 = min), mean of remaining 5; sorted order is fine
  if (tid < 64) {
    float s5 = 0.f;
#pragma unroll
    for (int k = 1; k < KSEL; ++k) s5 += __uint_as_float(cand[0][tid][k]);
    value[b * NPTS + g0 + tid] = s5 * 0.2f;
  }
}

// ---------------------------------------------------------------------------
// Kernel C: per-batch stats + masked mean * weight -> atomicAdd into out.
// ---------------------------------------------------------------------------
__global__ __launch_bounds__(256) void stats_kernel(const float* __restrict__ value,
                                                    const float* __restrict__ weights,
                                                    float* __restrict__ out) {
  __shared__ float red[256];
  const int b   = blockIdx.x;
  const int tid = threadIdx.x;
  const float* __restrict__ v = value + b * NPTS;

  float s = 0.f;
  for (int j = tid; j < NPTS; j += 256) s += v[j];
  red[tid] = s;
  __syncthreads();
  for (int off = 128; off > 0; off >>= 1) {
    if (tid < off) red[tid] += red[tid + off];
    __syncthreads();
  }
  const float mean = red[0] * (1.0f / NPTS);
  __syncthreads();

  float s2 = 0.f;
  for (int j = tid; j < NPTS; j += 256) {
    const float d = v[j] - mean;
    s2 += d * d;
  }
  red[tid] = s2;
  __syncthreads();
  for (int off = 128; off > 0; off >>= 1) {
    if (tid < off) red[tid] += red[tid + off];
    __syncthreads();
  }
  const float thr = mean + ALPHA * sqrtf(red[0] * (1.0f / (NPTS - 1)));
  __syncthreads();

  float s3 = 0.f;
  for (int j = tid; j < NPTS; j += 256) {
    const float vv = v[j];
    if (vv > thr) s3 += vv;
  }
  red[tid] = s3;
  __syncthreads();
  for (int off = 128; off > 0; off >>= 1) {
    if (tid < off) red[tid] += red[tid + off];
    __syncthreads();
  }
  if (tid == 0) {
    atomicAdd(out, red[0] * (1.0f / NPTS) * weights[b] * (1.0f / BATCH));
  }
}

extern "C" void kernel_launch(void* const* d_in, const int* in_sizes, int n_in,
                              void* d_out, int out_size, void* d_ws, size_t ws_size,
                              hipStream_t stream) {
  const float* pc      = (const float*)d_in[0];   // [8,4096,3] f32
  const float* weights = (const float*)d_in[1];   // [8] f32
  float* out   = (float*)d_out;                   // scalar f32
  float* value = (float*)d_ws;                    // [8*4096]

  float* xs_g = value + 32768;
  float* ys_g = xs_g + 32768;
  float* zs_g = ys_g + 32768;
  int* starts_g = (int*)(zs_g + 32768);

  bucket_kernel<<<dim3(BATCH), dim3(1024), 0, stream>>>(pc, xs_g, ys_g, zs_g, starts_g, out);
  knn_window_kernel<<<dim3(BATCH * 64), dim3(1024), 0, stream>>>(xs_g, ys_g, zs_g, starts_g, value);
  stats_kernel<<<dim3(BATCH), dim3(256), 0, stream>>>(value, weights, out);
}